// Round 1
// baseline (283.064 us; speedup 1.0000x reference)
//
#include <hip/hip_runtime.h>

// BaseEncoder: x[B,F] fp32 -> out[B,F,32] fp32
//   out[...,0]   = (x < 0) ? 1 : 0
//   out[...,1+d] = bit (30-d) of bitcast(x)   (bits 30..0; abs() only clears
//                  bit 31, so bits 30..0 of x equal bits 30..0 of |x|)
//
// R5: exact-trip-count store-stream kernel. The rocclr fill kernel sustains
// 6.36 TB/s on this chip at ~10% occupancy (2048x256, 32 NT dwordx4 stores
// per thread, no predicates). We replicate that exactly:
//   - each thread owns exactly 32 output quads (n_quads = 32 * 524288 exact)
//   - zero bounds checks in the hot kernel
//   - ALL 32 input loads issued up-front (phase 1) so the 32 NT stores
//     (phase 2) form an unbroken 1 KiB/wave-instr store stream; s_waitcnt
//     vmcnt(N) counts down monotonically instead of draining per batch.
// Mapping unchanged: 8 threads per input element, 4 consecutive channels
// each -> consecutive lanes store consecutive 16B. Channel phase j0 and the
// four shift amounts are thread-invariant (hoisted once).

typedef float f32x4 __attribute__((ext_vector_type(4)));

constexpr int BLOCK = 256;
constexpr int GRID = 2048;              // 8 blocks/CU on 256 CUs
constexpr int STRIDE = GRID * BLOCK;    // 524288 quads per sweep
constexpr int STEPS = 32;               // exact: n_quads == STEPS * STRIDE

__global__ __launch_bounds__(BLOCK) void base_encoder_exact(
    const float* __restrict__ x, f32x4* __restrict__ out) {
  const int tid = blockIdx.x * BLOCK + threadIdx.x;
  const int j0 = (tid & 7) << 2;        // channel phase, thread-invariant
  const bool sign_lane = (j0 == 0);
  const int s1 = 30 - j0, s2 = 29 - j0, s3 = 28 - j0;

  // Phase 1: issue all 32 loads. 8 consecutive lanes share each element
  // (same-address lanes broadcast in L1); element stride per step is
  // STRIDE/8 = 65536 floats. Static indices -> xv[] stays in VGPRs.
  float xv[STEPS];
  const int e0 = tid >> 3;
#pragma unroll
  for (int k = 0; k < STEPS; ++k)
    xv[k] = x[e0 + k * (STRIDE / 8)];

  // Phase 2: convert + unbroken NT store stream (1 KiB per wave store).
#pragma unroll
  for (int k = 0; k < STEPS; ++k) {
    const unsigned r = __float_as_uint(xv[k]);
    f32x4 o;
    // j0==0: channel 0 is the exact sign channel (x<0), NOT the sign bit
    // (keeps -0.0 semantics identical to the reference).
    o.x = sign_lane ? ((xv[k] < 0.0f) ? 1.0f : 0.0f)
                    : (float)((r >> (31 - j0)) & 1u);
    o.y = (float)((r >> s1) & 1u);
    o.z = (float)((r >> s2) & 1u);
    o.w = (float)((r >> s3) & 1u);
    __builtin_nontemporal_store(o, &out[tid + k * STRIDE]);
  }
}

// Fallback for shapes that don't divide exactly (kept from R4).
constexpr int BATCH = 4;
__global__ __launch_bounds__(BLOCK) void base_encoder_gs(
    const float* __restrict__ x, f32x4* __restrict__ out, int n_quads) {
  const int stride = GRID * BLOCK;
  int tid = blockIdx.x * BLOCK + threadIdx.x;
  const int j0 = (tid & 7) << 2;
  const bool sign_lane = (j0 == 0);

  for (int base = tid; base < n_quads; base += BATCH * stride) {
    int idx[BATCH];
    float xv[BATCH];
#pragma unroll
    for (int k = 0; k < BATCH; ++k) {
      idx[k] = base + k * stride;
      xv[k] = (idx[k] < n_quads) ? x[idx[k] >> 3] : 0.0f;
    }
#pragma unroll
    for (int k = 0; k < BATCH; ++k) {
      if (idx[k] < n_quads) {
        unsigned r = __float_as_uint(xv[k]);
        f32x4 o;
        o.x = (float)((r >> (31 - j0)) & 1u);
        o.y = (float)((r >> (30 - j0)) & 1u);
        o.z = (float)((r >> (29 - j0)) & 1u);
        o.w = (float)((r >> (28 - j0)) & 1u);
        if (sign_lane) o.x = (xv[k] < 0.0f) ? 1.0f : 0.0f;
        __builtin_nontemporal_store(o, &out[idx[k]]);
      }
    }
  }
}

extern "C" void kernel_launch(void* const* d_in, const int* in_sizes, int n_in,
                              void* d_out, int out_size, void* d_ws, size_t ws_size,
                              hipStream_t stream) {
  const float* x = (const float*)d_in[0];
  f32x4* out = (f32x4*)d_out;
  int n_elems = in_sizes[0];            // 4096*512 = 2,097,152
  int n_quads = n_elems * 8;            // 16,777,216 = STEPS * STRIDE exactly
  if (n_quads == STEPS * STRIDE) {
    base_encoder_exact<<<GRID, BLOCK, 0, stream>>>(x, out);
  } else {
    base_encoder_gs<<<GRID, BLOCK, 0, stream>>>(x, out, n_quads);
  }
}

// Round 2
// 269.564 us; speedup vs baseline: 1.0501x; 1.0501x over previous
//
#include <hip/hip_runtime.h>

// BaseEncoder: x[B,F] fp32 -> out[B,F,32] fp32
//   out[...,0]   = (x < 0) ? 1 : 0
//   out[...,1+d] = bit (30-d) of bitcast(x)   (bits 30..0; abs() only clears
//                  bit 31, so bits 30..0 of x equal bits 30..0 of |x|)
//
// R6: LDS-staged, block-contiguous store-stream kernel.
//
// Post-mortem R5: issuing 32 skinny (32B-useful) loads up-front REGRESSED
// (+11us) -- loads and NT stores share vmcnt, so every store wait is
// conservative over a mixed queue. The 6.4 TB/s fill kernel's key property
// is a store stream with ZERO vmcnt dependencies.
//
// R6 structure: block b owns the contiguous output range
//   quads [b*8192, (b+1)*8192)  (128 KiB), store addr = b*8192 + k*256 + tid
// so its input is the contiguous range x[b*1024 .. b*1024+1024)  (4 KiB):
//   element(q) = q>>3 = b*1024 + k*32 + (tid>>3), phase = tid&7.
// Phase 1: 256 threads load 1024 floats as coalesced float4 -> LDS (4 KiB).
// Phase 2: one barrier, then 32 NT dwordx4 stores fed by ds_read_b32
//   broadcasts (8 lanes/word, 8 words/wave -> 8 banks, conflict-free).
//   The store stream carries only lgkmcnt waits; vmcnt stays monotone like
//   the fill kernel. Per-block contiguous 128 KiB also beats the old 8 MiB
//   grid-interleave for DRAM page locality.

typedef float f32x4 __attribute__((ext_vector_type(4)));

constexpr int BLOCK = 256;
constexpr int GRID = 2048;                 // 8 blocks/CU on 256 CUs, all resident
constexpr int STEPS = 32;                  // quads per thread
constexpr int QUADS_PER_BLOCK = BLOCK * STEPS;     // 8192 quads = 128 KiB out
constexpr int ELEMS_PER_BLOCK = QUADS_PER_BLOCK / 8; // 1024 floats = 4 KiB in

__global__ __launch_bounds__(BLOCK) void base_encoder_lds(
    const float* __restrict__ x, f32x4* __restrict__ out) {
  __shared__ float smem[ELEMS_PER_BLOCK];

  const int t = threadIdx.x;
  const int b = blockIdx.x;

  // Phase 1: coalesced stage-in. 1 KiB per wave-load, 4 KiB per block.
  const f32x4 v = *reinterpret_cast<const f32x4*>(x + b * ELEMS_PER_BLOCK + t * 4);
  *reinterpret_cast<f32x4*>(&smem[t * 4]) = v;
  __syncthreads();

  const int g = t >> 3;                    // element slot within a 32-wide row
  const int j0 = (t & 7) << 2;             // channel phase, thread-invariant
  const bool sign_lane = (j0 == 0);
  const int s0 = 31 - j0, s1 = 30 - j0, s2 = 29 - j0, s3 = 28 - j0;
  f32x4* const op = out + b * QUADS_PER_BLOCK + t;

  // Phase 2: pure store stream; ds_read_b32 broadcast feeds each step.
#pragma unroll
  for (int k = 0; k < STEPS; ++k) {
    const float xv = smem[k * 32 + g];
    const unsigned r = __float_as_uint(xv);
    f32x4 o;
    // channel 0 is the exact sign channel (x<0), not the sign bit:
    // keeps -0.0 / NaN semantics identical to the reference.
    o.x = sign_lane ? ((xv < 0.0f) ? 1.0f : 0.0f)
                    : (float)((r >> s0) & 1u);
    o.y = (float)((r >> s1) & 1u);
    o.z = (float)((r >> s2) & 1u);
    o.w = (float)((r >> s3) & 1u);
    __builtin_nontemporal_store(o, op + k * BLOCK);
  }
}

// Fallback for shapes that don't divide exactly (kept from R4).
constexpr int BATCH = 4;
__global__ __launch_bounds__(BLOCK) void base_encoder_gs(
    const float* __restrict__ x, f32x4* __restrict__ out, int n_quads) {
  const int stride = GRID * BLOCK;
  int tid = blockIdx.x * BLOCK + threadIdx.x;
  const int j0 = (tid & 7) << 2;
  const bool sign_lane = (j0 == 0);

  for (int base = tid; base < n_quads; base += BATCH * stride) {
    int idx[BATCH];
    float xv[BATCH];
#pragma unroll
    for (int k = 0; k < BATCH; ++k) {
      idx[k] = base + k * stride;
      xv[k] = (idx[k] < n_quads) ? x[idx[k] >> 3] : 0.0f;
    }
#pragma unroll
    for (int k = 0; k < BATCH; ++k) {
      if (idx[k] < n_quads) {
        unsigned r = __float_as_uint(xv[k]);
        f32x4 o;
        o.x = (float)((r >> (31 - j0)) & 1u);
        o.y = (float)((r >> (30 - j0)) & 1u);
        o.z = (float)((r >> (29 - j0)) & 1u);
        o.w = (float)((r >> (28 - j0)) & 1u);
        if (sign_lane) o.x = (xv[k] < 0.0f) ? 1.0f : 0.0f;
        __builtin_nontemporal_store(o, &out[idx[k]]);
      }
    }
  }
}

extern "C" void kernel_launch(void* const* d_in, const int* in_sizes, int n_in,
                              void* d_out, int out_size, void* d_ws, size_t ws_size,
                              hipStream_t stream) {
  const float* x = (const float*)d_in[0];
  f32x4* out = (f32x4*)d_out;
  int n_elems = in_sizes[0];               // 4096*512 = 2,097,152
  int n_quads = n_elems * 8;               // 16,777,216 = GRID * QUADS_PER_BLOCK
  if (n_quads == GRID * QUADS_PER_BLOCK) {
    base_encoder_lds<<<GRID, BLOCK, 0, stream>>>(x, out);
  } else {
    base_encoder_gs<<<GRID, BLOCK, 0, stream>>>(x, out, n_quads);
  }
}

// Round 3
// 262.567 us; speedup vs baseline: 1.0781x; 1.0266x over previous
//
#include <hip/hip_runtime.h>

// BaseEncoder: x[B,F] fp32 -> out[B,F,32] fp32
//   out[...,0]   = (x < 0) ? 1 : 0
//   out[...,1+d] = bit (30-d) of bitcast(x)   (bits 30..0; abs() only clears
//                  bit 31, so bits 30..0 of x equal bits 30..0 of |x|)
//
// R7: R6 structure with PLAIN (cached) stores instead of nontemporal.
//
// Evidence: R4/R5/R6 use three completely different load-side structures
// (interleaved broadcast loads / 32-deep load batch / LDS staging) and all
// land at the same ~100us kernel time (~2.6 TB/s effective) -- while the
// rocclr fill kernel on the SAME runs sustains 6.4 TB/s with FETCH_SIZE=0,
// i.e. plain cached stores of fully-covered lines neither read-allocate nor
// bottleneck. The one invariant across our versions was the NT store hint.
// Theory: NT (no-allocate/streaming) bypasses L2 write-combining, so 16B
// lane-stores reach the HBM controller un-aggregated and pay partial-burst
// cost (~2.5x loss). Output (256 MiB) >> L2 (32 MiB) so allocation policy
// buys nothing; drop NT, single-variable A/B.
//
// Structure (unchanged from R6): block b owns contiguous output quads
// [b*8192, (b+1)*8192) (128 KiB); its input is contiguous x[b*1024 ..
// b*1024+1024) (4 KiB), staged to LDS via one coalesced float4/thread.
// Store stream: 32 dwordx4 per thread fed by ds_read_b32 8-lane broadcasts
// (conflict-free), no vmcnt dependencies inside the stream.

typedef float f32x4 __attribute__((ext_vector_type(4)));

constexpr int BLOCK = 256;
constexpr int GRID = 2048;                 // 8 blocks/CU on 256 CUs
constexpr int STEPS = 32;                  // quads per thread
constexpr int QUADS_PER_BLOCK = BLOCK * STEPS;       // 8192 quads = 128 KiB out
constexpr int ELEMS_PER_BLOCK = QUADS_PER_BLOCK / 8; // 1024 floats = 4 KiB in

__global__ __launch_bounds__(BLOCK) void base_encoder_lds(
    const float* __restrict__ x, f32x4* __restrict__ out) {
  __shared__ float smem[ELEMS_PER_BLOCK];

  const int t = threadIdx.x;
  const int b = blockIdx.x;

  // Phase 1: coalesced stage-in. 1 KiB per wave-load, 4 KiB per block.
  const f32x4 v = *reinterpret_cast<const f32x4*>(x + b * ELEMS_PER_BLOCK + t * 4);
  *reinterpret_cast<f32x4*>(&smem[t * 4]) = v;
  __syncthreads();

  const int g = t >> 3;                    // element slot within a 32-wide row
  const int j0 = (t & 7) << 2;             // channel phase, thread-invariant
  const bool sign_lane = (j0 == 0);
  const int s0 = 31 - j0, s1 = 30 - j0, s2 = 29 - j0, s3 = 28 - j0;
  f32x4* const op = out + b * QUADS_PER_BLOCK + t;

  // Phase 2: store stream via plain cached stores (L2 write-combines full
  // 64B lines; FETCH stays ~0 per the fill kernel's counters).
#pragma unroll
  for (int k = 0; k < STEPS; ++k) {
    const float xv = smem[k * 32 + g];
    const unsigned r = __float_as_uint(xv);
    f32x4 o;
    // channel 0 is the exact sign channel (x<0), not the sign bit:
    // keeps -0.0 / NaN semantics identical to the reference.
    o.x = sign_lane ? ((xv < 0.0f) ? 1.0f : 0.0f)
                    : (float)((r >> s0) & 1u);
    o.y = (float)((r >> s1) & 1u);
    o.z = (float)((r >> s2) & 1u);
    o.w = (float)((r >> s3) & 1u);
    op[k * BLOCK] = o;
  }
}

// Fallback for shapes that don't divide exactly (kept from R4).
constexpr int BATCH = 4;
__global__ __launch_bounds__(BLOCK) void base_encoder_gs(
    const float* __restrict__ x, f32x4* __restrict__ out, int n_quads) {
  const int stride = GRID * BLOCK;
  int tid = blockIdx.x * BLOCK + threadIdx.x;
  const int j0 = (tid & 7) << 2;
  const bool sign_lane = (j0 == 0);

  for (int base = tid; base < n_quads; base += BATCH * stride) {
    int idx[BATCH];
    float xv[BATCH];
#pragma unroll
    for (int k = 0; k < BATCH; ++k) {
      idx[k] = base + k * stride;
      xv[k] = (idx[k] < n_quads) ? x[idx[k] >> 3] : 0.0f;
    }
#pragma unroll
    for (int k = 0; k < BATCH; ++k) {
      if (idx[k] < n_quads) {
        unsigned r = __float_as_uint(xv[k]);
        f32x4 o;
        o.x = (float)((r >> (31 - j0)) & 1u);
        o.y = (float)((r >> (30 - j0)) & 1u);
        o.z = (float)((r >> (29 - j0)) & 1u);
        o.w = (float)((r >> (28 - j0)) & 1u);
        if (sign_lane) o.x = (xv[k] < 0.0f) ? 1.0f : 0.0f;
        out[idx[k]] = o;
      }
    }
  }
}

extern "C" void kernel_launch(void* const* d_in, const int* in_sizes, int n_in,
                              void* d_out, int out_size, void* d_ws, size_t ws_size,
                              hipStream_t stream) {
  const float* x = (const float*)d_in[0];
  f32x4* out = (f32x4*)d_out;
  int n_elems = in_sizes[0];               // 4096*512 = 2,097,152
  int n_quads = n_elems * 8;               // 16,777,216 = GRID * QUADS_PER_BLOCK
  if (n_quads == GRID * QUADS_PER_BLOCK) {
    base_encoder_lds<<<GRID, BLOCK, 0, stream>>>(x, out);
  } else {
    base_encoder_gs<<<GRID, BLOCK, 0, stream>>>(x, out, n_quads);
  }
}